// Round 8
// baseline (562.759 us; speedup 1.0000x reference)
//
#include <hip/hip_runtime.h>
#include <hip/hip_bf16.h>

// Model dims
#define BB 32
#define QL_ 20
#define DL_ 64
#define BL_ 512
#define MN_ 8
#define ML_ 16
#define DD 128
#define HH 8

// concatenated row-space for MHA: [dcq | d | b]; eq appended for gather only
#define ROWS_DCQ 4096
#define ROWS_D   2048
#define ROWS_B   16384
#define R_ALL    22528
#define ROWS_EQ  640
#define R_GATHER 23168

typedef float f2 __attribute__((ext_vector_type(2)));

// ---------------- fused gather (+norms) + zero of knrm accumulators ----------------
__global__ __launch_bounds__(256) void gather_all(
    const int* __restrict__ in_q, const int* __restrict__ in_d,
    const int* __restrict__ in_dcq, const int* __restrict__ in_db,
    const float* __restrict__ emb, float* __restrict__ x_all, float* __restrict__ ytmp,
    float* __restrict__ inv_eq, float* __restrict__ inv_ed, float* __restrict__ inv_eb,
    float* __restrict__ zero_p, int nzero) {
    int blk = blockIdx.x;
    if (blk >= 2896) {                      // zero tail
        int i = (blk - 2896) * 256 + threadIdx.x;
        if (i < nzero) zero_p[i] = 0.f;
        return;
    }
    int t = blk * 256 + threadIdx.x;
    int r = t >> 5, c = t & 31;
    const int* idx; float* outp; float* invp; int lr;
    if (r < ROWS_DCQ)              { idx = in_dcq; outp = ytmp + (size_t)r * DD;  invp = nullptr; lr = r; }
    else if (r < ROWS_DCQ + ROWS_D){ idx = in_d;   outp = x_all + (size_t)r * DD; invp = inv_ed;  lr = r - ROWS_DCQ; }
    else if (r < R_ALL)            { idx = in_db;  outp = x_all + (size_t)r * DD; invp = inv_eb;  lr = r - (ROWS_DCQ + ROWS_D); }
    else                           { idx = in_q;   outp = x_all + (size_t)r * DD; invp = inv_eq;  lr = r - R_ALL; }
    float4 val = ((const float4*)(emb + (size_t)idx[lr] * DD))[c];
    ((float4*)outp)[c] = val;
    float ss = val.x * val.x + val.y * val.y + val.z * val.z + val.w * val.w;
    ss += __shfl_xor(ss, 1, 64);
    ss += __shfl_xor(ss, 2, 64);
    ss += __shfl_xor(ss, 4, 64);
    ss += __shfl_xor(ss, 8, 64);
    ss += __shfl_xor(ss, 16, 64);
    if (c == 0 && invp) invp[lr] = 1.0f / fmaxf(sqrtf(ss), 1e-12f);
}

// ---------------- linear 128->128 + relu, 8x8 register tile ----------------
__device__ __forceinline__ void linear_body(float* __restrict__ wT, float* __restrict__ bs,
                                            const float* __restrict__ in, const float* __restrict__ W,
                                            const float* __restrict__ bias, float* __restrict__ out,
                                            float* __restrict__ inv_out, int block) {
    int t = threadIdx.x;
    for (int i = t; i < DD * DD; i += 256) {
        int o = i >> 7, e = i & 127;
        wT[e * 132 + o] = W[i];
    }
    if (t < 128) bs[t] = bias[t];
    __syncthreads();
    int og = t & 15, rg = t >> 4;
    int rowbase = block * 128 + rg * 8;
    f2 acc[8][4];
#pragma unroll
    for (int r = 0; r < 8; r++)
#pragma unroll
        for (int p = 0; p < 4; p++) acc[r][p] = f2{0.f, 0.f};
    for (int e4 = 0; e4 < 32; e4++) {
        float4 xv[8];
#pragma unroll
        for (int r = 0; r < 8; r++)
            xv[r] = *(const float4*)&in[(size_t)(rowbase + r) * DD + 4 * e4];
#pragma unroll
        for (int ee = 0; ee < 4; ee++) {
            int e = 4 * e4 + ee;
            float4 wa = *(const float4*)&wT[e * 132 + 8 * og];
            float4 wb = *(const float4*)&wT[e * 132 + 8 * og + 4];
            f2 w0 = {wa.x, wa.y}, w1 = {wa.z, wa.w}, w2 = {wb.x, wb.y}, w3 = {wb.z, wb.w};
#pragma unroll
            for (int r = 0; r < 8; r++) {
                float x = ((const float*)&xv[r])[ee];
                f2 x2 = {x, x};
                acc[r][0] = __builtin_elementwise_fma(x2, w0, acc[r][0]);
                acc[r][1] = __builtin_elementwise_fma(x2, w1, acc[r][1]);
                acc[r][2] = __builtin_elementwise_fma(x2, w2, acc[r][2]);
                acc[r][3] = __builtin_elementwise_fma(x2, w3, acc[r][3]);
            }
        }
    }
    float4 ba = *(const float4*)&bs[8 * og];
    float4 bbv = *(const float4*)&bs[8 * og + 4];
    float ss[8];
#pragma unroll
    for (int r = 0; r < 8; r++) {
        float o0 = fmaxf(acc[r][0].x + ba.x, 0.f);
        float o1 = fmaxf(acc[r][0].y + ba.y, 0.f);
        float o2 = fmaxf(acc[r][1].x + ba.z, 0.f);
        float o3 = fmaxf(acc[r][1].y + ba.w, 0.f);
        float o4 = fmaxf(acc[r][2].x + bbv.x, 0.f);
        float o5 = fmaxf(acc[r][2].y + bbv.y, 0.f);
        float o6 = fmaxf(acc[r][3].x + bbv.z, 0.f);
        float o7 = fmaxf(acc[r][3].y + bbv.w, 0.f);
        float4 s1 = {o0, o1, o2, o3}, s2 = {o4, o5, o6, o7};
        float* op = out + (size_t)(rowbase + r) * DD + 8 * og;
        *(float4*)op = s1;
        *(float4*)(op + 4) = s2;
        ss[r] = o0 * o0 + o1 * o1 + o2 * o2 + o3 * o3 + o4 * o4 + o5 * o5 + o6 * o6 + o7 * o7;
    }
    if (inv_out) {
#pragma unroll
        for (int r = 0; r < 8; r++) {
            ss[r] += __shfl_xor(ss[r], 1, 64);
            ss[r] += __shfl_xor(ss[r], 2, 64);
            ss[r] += __shfl_xor(ss[r], 4, 64);
            ss[r] += __shfl_xor(ss[r], 8, 64);
        }
#pragma unroll
        for (int r = 0; r < 8; r++)
            if (og == r) inv_out[rowbase + r] = 1.0f / fmaxf(sqrtf(ss[r]), 1e-12f);
    }
}

__global__ __launch_bounds__(256) void lin_kernel(const float* __restrict__ in, const float* __restrict__ W,
                                                  const float* __restrict__ bias, float* __restrict__ out,
                                                  float* __restrict__ inv_out) {
    __shared__ float wT[DD * 132];
    __shared__ float bs[DD];
    linear_body(wT, bs, in, W, bias, out, inv_out, blockIdx.x);
}

__global__ __launch_bounds__(256) void qkv_all(const float* __restrict__ x,
                                               const float* __restrict__ Wq, const float* __restrict__ bq,
                                               const float* __restrict__ Wk, const float* __restrict__ bk,
                                               const float* __restrict__ Wv, const float* __restrict__ bv,
                                               float* __restrict__ q, float* __restrict__ k, float* __restrict__ v) {
    __shared__ float wT[DD * 132];
    __shared__ float bs[DD];
    int sel = blockIdx.x / 176, blk = blockIdx.x % 176;
    const float* W = (sel == 0) ? Wq : (sel == 1) ? Wk : Wv;
    const float* B = (sel == 0) ? bq : (sel == 1) ? bk : bv;
    float* O = (sel == 0) ? q : (sel == 1) ? k : v;
    linear_body(wT, bs, x, W, B, O, nullptr, blk);
}

// ---------------- L=512 attention v7: K in LDS, V from global (uniform broadcast) ----
// Block = (qh,b,h): 256 q-rows, all 512 keys. 256 thr = 4 waves = 4 key-groups.
// NR=4 rows/lane as two f2 pairs. V row address is wave-uniform -> VMEM/SMEM broadcast,
// off the contended LDS pipe. 32 KB LDS -> ~4 blocks/CU for latency hiding.
// Softmax without max-shift: algebraically identical; scores are tiny relu-dots/4.
__device__ __forceinline__ void attn512_v7(float* __restrict__ sm,
                                           const float* __restrict__ q, const float* __restrict__ k,
                                           const float* __restrict__ v, float* __restrict__ y,
                                           int b, int h, int qh) {
    float* ks = sm;                        // 512*16 = 8192 floats = 32 KB
    int t = threadIdx.x;
    const size_t base = (size_t)b * 512 * DD + h * 16;
    for (int i = t; i < 512 * 4; i += 256) {
        int j = i >> 2, c = i & 3;
        *(float4*)&ks[j * 16 + 4 * c] = *(const float4*)&k[base + (size_t)j * DD + 4 * c];
    }
    int kg = t >> 6, lane = t & 63;
    int r0 = qh * 256 + lane;              // absolute q rows r0, +64, +128, +192
    f2 qv[2][16];
#pragma unroll
    for (int p = 0; p < 2; p++) {
        const float* qa = q + base + (size_t)(r0 + p * 128) * DD;
        const float* qb2 = qa + 64 * DD;
#pragma unroll
        for (int c = 0; c < 4; c++) {
            float4 va = *(const float4*)(qa + 4 * c);
            float4 vb = *(const float4*)(qb2 + 4 * c);
            qv[p][4 * c + 0] = f2{va.x * 0.25f, vb.x * 0.25f};
            qv[p][4 * c + 1] = f2{va.y * 0.25f, vb.y * 0.25f};
            qv[p][4 * c + 2] = f2{va.z * 0.25f, vb.z * 0.25f};
            qv[p][4 * c + 3] = f2{va.w * 0.25f, vb.w * 0.25f};
        }
    }
    f2 acc[2][16];
    f2 l2[2] = {f2{0.f, 0.f}, f2{0.f, 0.f}};
#pragma unroll
    for (int p = 0; p < 2; p++)
#pragma unroll
        for (int e = 0; e < 16; e++) acc[p][e] = f2{0.f, 0.f};
    __syncthreads();
    int j0 = kg * 128;
    for (int j = j0; j < j0 + 128; j++) {
        const float* vp = v + base + (size_t)j * DD;   // wave-uniform address
        float kk[16], vv[16];
#pragma unroll
        for (int c = 0; c < 4; c++) {
            *(float4*)&kk[4 * c] = *(const float4*)&ks[j * 16 + 4 * c];
            *(float4*)&vv[4 * c] = *(const float4*)(vp + 4 * c);
        }
        f2 d0a = qv[0][0] * f2{kk[0], kk[0]};
        f2 d1a = qv[0][1] * f2{kk[1], kk[1]};
        f2 d0b = qv[1][0] * f2{kk[0], kk[0]};
        f2 d1b = qv[1][1] * f2{kk[1], kk[1]};
#pragma unroll
        for (int e = 2; e < 16; e += 2) {
            d0a = __builtin_elementwise_fma(qv[0][e], f2{kk[e], kk[e]}, d0a);
            d1a = __builtin_elementwise_fma(qv[0][e + 1], f2{kk[e + 1], kk[e + 1]}, d1a);
            d0b = __builtin_elementwise_fma(qv[1][e], f2{kk[e], kk[e]}, d0b);
            d1b = __builtin_elementwise_fma(qv[1][e + 1], f2{kk[e + 1], kk[e + 1]}, d1b);
        }
        f2 da = d0a + d1a, db = d0b + d1b;
        f2 pa = {__expf(da.x), __expf(da.y)};
        f2 pb = {__expf(db.x), __expf(db.y)};
        l2[0] += pa;
        l2[1] += pb;
#pragma unroll
        for (int e = 0; e < 16; e++) {
            f2 ve = {vv[e], vv[e]};
            acc[0][e] = __builtin_elementwise_fma(pa, ve, acc[0][e]);
            acc[1][e] = __builtin_elementwise_fma(pb, ve, acc[1][e]);
        }
    }
    __syncthreads();   // staging dead; reuse sm for partials: 256 rows x 17 = 4352 floats
#pragma unroll
    for (int g = 1; g < 4; g++) {
        if (kg == g) {
#pragma unroll
            for (int p = 0; p < 2; p++) {
                int lr = lane + p * 128;
                float* pa = &sm[lr * 17];
                float* pb = &sm[(lr + 64) * 17];
#pragma unroll
                for (int e = 0; e < 16; e++) { pa[e] = acc[p][e].x; pb[e] = acc[p][e].y; }
                pa[16] = l2[p].x;
                pb[16] = l2[p].y;
            }
        }
        __syncthreads();
        if (kg == 0) {
#pragma unroll
            for (int p = 0; p < 2; p++) {
                int lr = lane + p * 128;
                const float* pa = &sm[lr * 17];
                const float* pb = &sm[(lr + 64) * 17];
#pragma unroll
                for (int e = 0; e < 16; e++) { acc[p][e].x += pa[e]; acc[p][e].y += pb[e]; }
                l2[p].x += pa[16];
                l2[p].y += pb[16];
            }
        }
        __syncthreads();
    }
    if (kg == 0) {
#pragma unroll
        for (int p = 0; p < 2; p++) {
            float ix = 1.0f / l2[p].x, iy = 1.0f / l2[p].y;
            float o0[16], o1[16];
#pragma unroll
            for (int e = 0; e < 16; e++) { o0[e] = acc[p][e].x * ix; o1[e] = acc[p][e].y * iy; }
            float* yp0 = y + base + (size_t)(r0 + p * 128) * DD;
            float* yp1 = yp0 + 64 * DD;
#pragma unroll
            for (int c = 0; c < 4; c++) {
                *(float4*)(yp0 + 4 * c) = *(const float4*)&o0[4 * c];
                *(float4*)(yp1 + 4 * c) = *(const float4*)&o1[4 * c];
            }
        }
    }
}

// ---------------- small-L attention (e-split, 4 waves, V from global) ----------------
template <int L, int NQ>
__device__ __forceinline__ void attn_body(float* __restrict__ sm, const float* __restrict__ q,
                                          const float* __restrict__ k, const float* __restrict__ v,
                                          float* __restrict__ y, int b, int h) {
    constexpr int WAVES = 4;
    constexpr int WQ = L / (32 * NQ);
    constexpr int KG = WAVES / WQ;
    constexpr int KPG = L / KG;
    float* ks = sm;
    int t = threadIdx.x;
    const size_t base = (size_t)b * L * DD + h * 16;
    for (int i = t; i < L * 4; i += 256) {
        int j = i >> 2, c = i & 3;
        *(float4*)&ks[j * 16 + 4 * c] = *(const float4*)&k[base + (size_t)j * DD + 4 * c];
    }
    int w = t >> 6, lane = t & 63;
    int ls = lane & 31, eh = lane >> 5;
    int kg = w % KG, qw = w / KG;
    int qb2 = qw * 32 * NQ;
    f2 qv[NQ][4];
#pragma unroll
    for (int n = 0; n < NQ; n++) {
        int qr = qb2 + ls + 32 * n;
        const float* qp = q + base + (size_t)qr * DD + eh * 8;
        float4 a = *(const float4*)qp;
        float4 b4 = *(const float4*)(qp + 4);
        qv[n][0] = f2{a.x, a.y};   qv[n][1] = f2{a.z, a.w};
        qv[n][2] = f2{b4.x, b4.y}; qv[n][3] = f2{b4.z, b4.w};
    }
    f2 acc[NQ][4];
    float l[NQ];
#pragma unroll
    for (int n = 0; n < NQ; n++) {
#pragma unroll
        for (int m = 0; m < 4; m++) acc[n][m] = f2{0.f, 0.f};
        l[n] = 0.f;
    }
    __syncthreads();
    for (int j = kg * KPG; j < (kg + 1) * KPG; j++) {
        const float* vp = v + base + (size_t)j * DD + eh * 8;
        float4 ka = *(const float4*)&ks[j * 16 + eh * 8];
        float4 kb2 = *(const float4*)&ks[j * 16 + eh * 8 + 4];
        float4 va = *(const float4*)vp;
        float4 vb2 = *(const float4*)(vp + 4);
        f2 kk0 = {ka.x, ka.y}, kk1 = {ka.z, ka.w}, kk2 = {kb2.x, kb2.y}, kk3 = {kb2.z, kb2.w};
        f2 vv0 = {va.x, va.y}, vv1 = {va.z, va.w}, vv2 = {vb2.x, vb2.y}, vv3 = {vb2.z, vb2.w};
#pragma unroll
        for (int n = 0; n < NQ; n++) {
            f2 d2 = qv[n][0] * kk0;
            d2 = __builtin_elementwise_fma(qv[n][1], kk1, d2);
            d2 = __builtin_elementwise_fma(qv[n][2], kk2, d2);
            d2 = __builtin_elementwise_fma(qv[n][3], kk3, d2);
            float sh = d2.x + d2.y;
            float s = sh + __shfl_xor(sh, 32, 64);
            float p = __expf(s * 0.25f);
            l[n] += p;
            f2 p2 = {p, p};
            acc[n][0] = __builtin_elementwise_fma(p2, vv0, acc[n][0]);
            acc[n][1] = __builtin_elementwise_fma(p2, vv1, acc[n][1]);
            acc[n][2] = __builtin_elementwise_fma(p2, vv2, acc[n][2]);
            acc[n][3] = __builtin_elementwise_fma(p2, vv3, acc[n][3]);
        }
    }
    __syncthreads();
    if (KG > 1 && kg > 0) {
#pragma unroll
        for (int n = 0; n < NQ; n++) {
            int qr = qb2 + ls + 32 * n;
            float* pp = &sm[((kg - 1) * L + qr) * 20 + eh * 10];
            *(f2*)&pp[0] = acc[n][0];
            *(f2*)&pp[2] = acc[n][1];
            *(f2*)&pp[4] = acc[n][2];
            *(f2*)&pp[6] = acc[n][3];
            pp[8] = l[n];
        }
    }
    __syncthreads();
    if (kg == 0) {
#pragma unroll
        for (int n = 0; n < NQ; n++) {
            int qr = qb2 + ls + 32 * n;
            f2 a0 = acc[n][0], a1 = acc[n][1], a2 = acc[n][2], a3 = acc[n][3];
            float lt = l[n];
#pragma unroll
            for (int g = 1; g < KG; g++) {
                const float* pp = &sm[((g - 1) * L + qr) * 20 + eh * 10];
                a0 += *(const f2*)&pp[0];
                a1 += *(const f2*)&pp[2];
                a2 += *(const f2*)&pp[4];
                a3 += *(const f2*)&pp[6];
                lt += pp[8];
            }
            float inv = 1.0f / lt;
            float4 o1 = {a0.x * inv, a0.y * inv, a1.x * inv, a1.y * inv};
            float4 o2 = {a2.x * inv, a2.y * inv, a3.x * inv, a3.y * inv};
            float* yp = y + base + (size_t)qr * DD + eh * 8;
            *(float4*)yp = o1;
            *(float4*)(yp + 4) = o2;
        }
    }
}

// grid: [0,512) attn512 (blk = qh*256 + h*32 + b; blk%8=b%8 keeps batch on one XCD),
//       [512,768) L=128, [768,1024) L=64
__global__ __launch_bounds__(256, 4) void attn_all(const float* __restrict__ qb_, const float* __restrict__ kb_,
                                                   const float* __restrict__ vb_, float* __restrict__ yb_) {
    __shared__ float sm[8192];             // 32 KB
    int blk = blockIdx.x;
    if (blk < 512) {
        const size_t off = (size_t)(ROWS_DCQ + ROWS_D) * DD;
        int qh = blk >> 8, local = blk & 255;
        attn512_v7(sm, qb_ + off, kb_ + off, vb_ + off, yb_ + off, local & 31, local >> 5, qh);
    } else if (blk < 768) {
        int local = blk - 512;
        attn_body<128, 1>(sm, qb_, kb_, vb_, yb_, local & 31, local >> 5);
    } else {
        int local = blk - 768;
        const size_t off = (size_t)ROWS_DCQ * DD;
        attn_body<64, 1>(sm, qb_ + off, kb_ + off, vb_ + off, yb_ + off, local & 31, local >> 5);
    }
}

// ---------------- KNRM core: register-tiled sims + gaussian kernels ----------------
// RAW=true: atomically add raw ps sums (no log/mask) into out[qrow*11+kk] — used to
// split the d-range of one logical pass across blocks (log(Σ) done later in final).
template <int QPT, int DPT, bool RAW>
__device__ void knrm_core(float* __restrict__ sm,
                          const float* __restrict__ Q, const float* __restrict__ invQ,
                          const float* __restrict__ mq, int QL, int q0, int qbase,
                          const float* __restrict__ D, const float* __restrict__ invD,
                          const float* __restrict__ md, int DL, int dbase, int mdbase,
                          float* __restrict__ out) {
    constexpr int QT = QPT * 16, DT = DPT * 16;
    float* qtile = sm;
    float* dtile = qtile + QT * 132;
    float* mdv = dtile + DT * 132;
    float* red = mdv + DT;
    float* outred = red + 4 * 16 * QPT * 11;
    const float MUc[11] = {1.0f, 0.9f, 0.7f, 0.5f, 0.3f, 0.1f, -0.1f, -0.3f, -0.5f, -0.7f, -0.9f};
    const float NC[11]  = {-500000.0f, -50.f, -50.f, -50.f, -50.f, -50.f, -50.f, -50.f, -50.f, -50.f, -50.f};
    int t = threadIdx.x;
    int tq = t & 15, td = t >> 4;
    if (!RAW && t < 11) outred[t] = 0.f;
    for (int i = t; i < QT * 32; i += 256) {
        int r = i >> 5, c = i & 31;
        int qrow = q0 + r;
        float4 val = make_float4(0.f, 0.f, 0.f, 0.f);
        if (qrow < QL) {
            float s = invQ[qbase + qrow];
            float4 g = *(const float4*)(Q + (size_t)(qbase + qrow) * DD + 4 * c);
            val = make_float4(g.x * s, g.y * s, g.z * s, g.w * s);
        }
        *(float4*)&qtile[r * 132 + 4 * c] = val;
    }
    float ps[QPT][11];
#pragma unroll
    for (int i = 0; i < QPT; i++)
#pragma unroll
        for (int kk = 0; kk < 11; kk++) ps[i][kk] = 0.f;

    for (int d0 = 0; d0 < DL; d0 += DT) {
        for (int i = t; i < DT * 32; i += 256) {
            int r = i >> 5, c = i & 31;
            int drow = d0 + r;
            float4 val = make_float4(0.f, 0.f, 0.f, 0.f);
            if (drow < DL) {
                float s = invD[dbase + drow];
                float4 g = *(const float4*)(D + (size_t)(dbase + drow) * DD + 4 * c);
                val = make_float4(g.x * s, g.y * s, g.z * s, g.w * s);
            }
            *(float4*)&dtile[r * 132 + 4 * c] = val;
        }
        if (t < DT) mdv[t] = (d0 + t < DL) ? md[mdbase + d0 + t] : 0.f;
        __syncthreads();
        float dot[QPT][DPT];
#pragma unroll
        for (int i = 0; i < QPT; i++)
#pragma unroll
            for (int j = 0; j < DPT; j++) dot[i][j] = 0.f;
#pragma unroll 2
        for (int e4 = 0; e4 < 32; e4++) {
            float4 qv[QPT], dv[DPT];
#pragma unroll
            for (int i = 0; i < QPT; i++) qv[i] = *(const float4*)&qtile[(tq + 16 * i) * 132 + 4 * e4];
#pragma unroll
            for (int j = 0; j < DPT; j++) dv[j] = *(const float4*)&dtile[(td + 16 * j) * 132 + 4 * e4];
#pragma unroll
            for (int i = 0; i < QPT; i++)
#pragma unroll
                for (int j = 0; j < DPT; j++)
                    dot[i][j] += qv[i].x * dv[j].x + qv[i].y * dv[j].y + qv[i].z * dv[j].z + qv[i].w * dv[j].w;
        }
#pragma unroll
        for (int j = 0; j < DPT; j++) {
            float m = mdv[td + 16 * j];
#pragma unroll
            for (int i = 0; i < QPT; i++) {
                float sim = dot[i][j];
#pragma unroll
                for (int kk = 0; kk < 11; kk++) {
                    float df = sim - MUc[kk];
                    ps[i][kk] = fmaf(__expf(df * df * NC[kk]), m, ps[i][kk]);
                }
            }
        }
        __syncthreads();
    }
#pragma unroll
    for (int i = 0; i < QPT; i++)
#pragma unroll
        for (int kk = 0; kk < 11; kk++) {
            ps[i][kk] += __shfl_xor(ps[i][kk], 16, 64);
            ps[i][kk] += __shfl_xor(ps[i][kk], 32, 64);
        }
    int w = t >> 6;
    if ((t & 63) < 16) {
#pragma unroll
        for (int i = 0; i < QPT; i++)
#pragma unroll
            for (int kk = 0; kk < 11; kk++) red[(w * 16 + tq) * (QPT * 11) + i * 11 + kk] = ps[i][kk];
    }
    __syncthreads();
    for (int i = t; i < 16 * QPT * 11; i += 256) {
        int tq2 = i / (QPT * 11);
        int rem = i - tq2 * (QPT * 11);
        int qi = rem / 11, kk = rem - qi * 11;
        float s = red[(0 * 16 + tq2) * (QPT * 11) + qi * 11 + kk] + red[(1 * 16 + tq2) * (QPT * 11) + qi * 11 + kk]
                + red[(2 * 16 + tq2) * (QPT * 11) + qi * 11 + kk] + red[(3 * 16 + tq2) * (QPT * 11) + qi * 11 + kk];
        int qrow = q0 + tq2 + 16 * qi;
        if (qrow < QL) {
            if (RAW) {
                atomicAdd(&out[qrow * 11 + kk], s);
            } else {
                float lps = logf(fmaxf(s, 1e-10f)) * mq[qbase + qrow] * 0.01f;
                atomicAdd(&outred[kk], lps);
            }
        }
    }
    if (!RAW) {
        __syncthreads();
        if (t < 11) atomicAdd(&out[t], outred[t]);
    }
}

// grid: [0,32) qd | [32,544) qb raw-chunks (16 per b) | [544,5408) kq/kd/kb (19 per (b,inst))
__global__ __launch_bounds__(256) void knrm_all(
    const float* __restrict__ eq, const float* __restrict__ inv_eq, const float* __restrict__ mask_q,
    const float* __restrict__ ed, const float* __restrict__ inv_ed, const float* __restrict__ mask_d,
    const float* __restrict__ eb, const float* __restrict__ inv_eb, const float* __restrict__ mask_db,
    const float* __restrict__ enc_d, const float* __restrict__ inv_encd,
    const float* __restrict__ enc_b, const float* __restrict__ inv_encb,
    const float* __restrict__ enc_dcq, const float* __restrict__ inv_encdcq, const float* __restrict__ mask_dcq,
    float* __restrict__ qdk, float* __restrict__ ps_qb,
    float* __restrict__ kq, float* __restrict__ kd, float* __restrict__ kb) {
    __shared__ float sm[9920];
    int blk = blockIdx.x;
    if (blk < 32) {
        int b = blk;
        knrm_core<2, 2, false>(sm, eq, inv_eq, mask_q, QL_, 0, b * QL_,
                               ed, inv_ed, mask_d, DL_, b * DL_, b * DL_, qdk + b * 11);
    } else if (blk < 544) {
        int u = blk - 32;
        int b = u & 31, ch = u >> 5;      // 16 chunks of 32 keys over BL=512
        knrm_core<2, 2, true>(sm, eq, inv_eq, mask_q, QL_, 0, b * QL_,
                              eb, inv_eb, mask_db, 32, b * BL_ + ch * 32, b * BL_ + ch * 32,
                              ps_qb + b * (QL_ * 11));
    } else {
        int u = blk - 544;
        int g = u / 19, sub = u % 19;
        int b = g & 31, inst = g >> 5;
        int dbase = b * (MN_ * ML_) + inst * ML_;
        if (sub == 0)
            knrm_core<2, 1, false>(sm, eq, inv_eq, mask_q, QL_, 0, b * QL_,
                                   enc_dcq, inv_encdcq, mask_dcq, ML_, dbase, dbase,
                                   kq + (size_t)(inst * BB + b) * 11);
        else if (sub < 3)
            knrm_core<2, 1, false>(sm, enc_d, inv_encd, mask_d, DL_, (sub - 1) * 32, b * DL_,
                                   enc_dcq, inv_encdcq, mask_dcq, ML_, dbase, dbase,
                                   kd + (size_t)(inst * BB + b) * 11);
        else
            knrm_core<2, 1, false>(sm, enc_b, inv_encb, mask_db, BL_, (sub - 3) * 32, b * BL_,
                                   enc_dcq, inv_encdcq, mask_dcq, ML_, dbase, dbase,
                                   kb + (size_t)(inst * BB + b) * 11);
    }
}

// ---------------- final combine (also finishes qb: log of summed ps partials) --------
__device__ inline float dot11(const float* w, const float* x) {
    float s = 0.f;
#pragma unroll
    for (int k = 0; k < 11; k++) s += w[k] * x[k];
    return s;
}

__global__ __launch_bounds__(384) void final_kernel(
    const float* __restrict__ qdk, const float* __restrict__ ps_qb, const float* __restrict__ mask_q,
    const float* __restrict__ kq, const float* __restrict__ kd, const float* __restrict__ kb,
    const float* qdW, const float* qdb, const float* qbW, const float* qbb,
    const float* qcqW, const float* qcqb, const float* dcqW, const float* dcqb,
    const float* bcqW, const float* bcqb, const float* expW, const float* expb,
    const float* combW, const float* combb, float* __restrict__ out) {
    __shared__ float qbk_s[BB * 11];
    int t = threadIdx.x;
    if (t < BB * 11) {
        int b = t / 11, kk = t % 11;
        float s = 0.f;
        for (int qq = 0; qq < QL_; qq++)
            s += logf(fmaxf(ps_qb[b * (QL_ * 11) + qq * 11 + kk], 1e-10f)) * mask_q[b * QL_ + qq];
        qbk_s[t] = s * 0.01f;
    }
    __syncthreads();
    int b = t;
    if (b >= BB) return;
    float qd = tanhf(dot11(qdW, qdk + b * 11) + qdb[0]);
    float qb = tanhf(dot11(qbW, qbk_s + b * 11) + qbb[0]);
    float qcqd = 0.f, qcqb2 = 0.f;
    for (int i = 0; i < MN_; i++) {
        int base = (i * BB + b) * 11;
        float r  = tanhf(dot11(qcqW, kq + base) + qcqb[0]);
        float da = tanhf(dot11(dcqW, kd + base) + dcqb[0]);
        float ba = tanhf(dot11(bcqW, kb + base) + bcqb[0]);
        qcqd += r * da;
        qcqb2 += r * ba;
    }
    float qcq = expW[0] * qcqd + expW[1] * qcqb2 + expb[0];
    out[b] = tanhf(combW[0] * qd + combW[1] * qb + combW[2] * qcq + combb[0]);
}

extern "C" void kernel_launch(void* const* d_in, const int* in_sizes, int n_in,
                              void* d_out, int out_size, void* d_ws, size_t ws_size,
                              hipStream_t stream) {
    const int*   in_q    = (const int*)d_in[0];
    const int*   in_d    = (const int*)d_in[1];
    const int*   in_dcq  = (const int*)d_in[2];
    const int*   in_db   = (const int*)d_in[3];
    const float* mask_q  = (const float*)d_in[4];
    const float* mask_d  = (const float*)d_in[5];
    const float* mask_dcq= (const float*)d_in[6];
    const float* mask_db = (const float*)d_in[7];
    const float* emb     = (const float*)d_in[8];
    const float* Wq = (const float*)d_in[9];   const float* bq = (const float*)d_in[10];
    const float* Wk = (const float*)d_in[11];  const float* bk = (const float*)d_in[12];
    const float* Wv = (const float*)d_in[13];  const float* bv = (const float*)d_in[14];
    const float* Wo = (const float*)d_in[15];  const float* bo = (const float*)d_in[16];
    const float* tW = (const float*)d_in[17];  const float* tb = (const float*)d_in[18];
    const float* qdW = (const float*)d_in[19]; const float* qdb = (const float*)d_in[20];
    const float* qbW = (const float*)d_in[21]; const float* qbb = (const float*)d_in[22];
    const float* qcqW = (const float*)d_in[23];const float* qcqb = (const float*)d_in[24];
    const float* dcqW = (const float*)d_in[25];const float* dcqb = (const float*)d_in[26];
    const float* bcqW = (const float*)d_in[27];const float* bcqb = (const float*)d_in[28];
    const float* expW = (const float*)d_in[29];const float* expb = (const float*)d_in[30];
    const float* combW = (const float*)d_in[31];const float* combb = (const float*)d_in[32];
    float* out = (float*)d_out;

    float* ws = (float*)d_ws;
    size_t off = 0;
    auto alloc = [&](size_t n) { float* p = ws + off; off += n; return p; };
    float* x_all = alloc((size_t)R_GATHER * DD);   // [dcq|d|b|eq] embeddings / projected dcq
    float* qbuf  = alloc((size_t)R_ALL * DD);      // q proj; attn writes y in-place here
    float* kbuf  = alloc((size_t)R_ALL * DD);      // gather tmp -> k proj -> enc_all
    float* vbuf  = alloc((size_t)R_ALL * DD);
    float* inv_eq  = alloc(ROWS_EQ);
    float* inv_ed  = alloc(ROWS_D);
    float* inv_eb  = alloc(ROWS_B);
    float* inv_enc = alloc(R_ALL);
    float* qdk   = alloc(BB * 11);                 // [qdk|kq|kd|kb|ps_qb] contiguous, zeroed in gather
    float* kq    = alloc(MN_ * BB * 11);
    float* kd    = alloc(MN_ * BB * 11);
    float* kb    = alloc(MN_ * BB * 11);
    float* ps_qb = alloc(BB * QL_ * 11);
    (void)ws_size; (void)in_sizes; (void)n_in; (void)out_size;
    const int kZeroCount = BB * 11 + 3 * MN_ * BB * 11 + BB * QL_ * 11;   // 15840

    const float* eq      = x_all + (size_t)R_ALL * DD;
    const float* ed      = x_all + (size_t)ROWS_DCQ * DD;
    const float* eb      = x_all + (size_t)(ROWS_DCQ + ROWS_D) * DD;
    float* enc_all = kbuf;
    const float* enc_dcq = enc_all;
    const float* enc_d   = enc_all + (size_t)ROWS_DCQ * DD;
    const float* enc_b   = enc_all + (size_t)(ROWS_DCQ + ROWS_D) * DD;
    const float* inv_encdcq = inv_enc;
    const float* inv_encd   = inv_enc + ROWS_DCQ;
    const float* inv_encb   = inv_enc + ROWS_DCQ + ROWS_D;

    // 1. gathers + emb norms + zero knrm accumulators (dcq raw emb -> kbuf tmp)
    gather_all<<<2896 + (kZeroCount + 255) / 256, 256, 0, stream>>>(in_q, in_d, in_dcq, in_db, emb,
                                                                    x_all, kbuf, inv_eq, inv_ed, inv_eb,
                                                                    qdk, kZeroCount);
    // 2. t-projection: raw dcq emb (kbuf[0:4096]) -> x_all[0:4096]
    lin_kernel<<<ROWS_DCQ / 128, 256, 0, stream>>>(kbuf, tW, tb, x_all, nullptr);
    // 3. q/k/v projections over all 22528 rows in one launch
    qkv_all<<<3 * (R_ALL / 128), 256, 0, stream>>>(x_all, Wq, bq, Wk, bk, Wv, bv, qbuf, kbuf, vbuf);
    // 4. all three attentions in one launch; y written in-place into qbuf
    attn_all<<<1024, 256, 0, stream>>>(qbuf, kbuf, vbuf, qbuf);
    // 5. out-projection over all rows + fused enc norms (kbuf becomes enc_all)
    lin_kernel<<<R_ALL / 128, 256, 0, stream>>>(qbuf, Wo, bo, enc_all, inv_enc);
    // 6. all 26 KNRM reductions (qb as raw-partial chunks)
    knrm_all<<<5408, 256, 0, stream>>>(eq, inv_eq, mask_q, ed, inv_ed, mask_d, eb, inv_eb, mask_db,
                                       enc_d, inv_encd, enc_b, inv_encb, enc_dcq, inv_encdcq, mask_dcq,
                                       qdk, ps_qb, kq, kd, kb);
    // 7. final combine (+ qb log-finish)
    final_kernel<<<1, 384, 0, stream>>>(qdk, ps_qb, mask_q, kq, kd, kb,
                                        qdW, qdb, qbW, qbb, qcqW, qcqb, dcqW, dcqb,
                                        bcqW, bcqb, expW, expb, combW, combb, out);
}

// Round 9
// 355.345 us; speedup vs baseline: 1.5837x; 1.5837x over previous
//
#include <hip/hip_runtime.h>
#include <hip/hip_bf16.h>

// Model dims
#define BB 32
#define QL_ 20
#define DL_ 64
#define BL_ 512
#define MN_ 8
#define ML_ 16
#define DD 128
#define HH 8

// concatenated row-space for MHA: [dcq | d | b]; eq appended for gather only
#define ROWS_DCQ 4096
#define ROWS_D   2048
#define ROWS_B   16384
#define R_ALL    22528
#define ROWS_EQ  640
#define R_GATHER 23168

typedef float f2 __attribute__((ext_vector_type(2)));

// ---------------- fused gather (+norms) + zero of knrm accumulators ----------------
__global__ __launch_bounds__(256) void gather_all(
    const int* __restrict__ in_q, const int* __restrict__ in_d,
    const int* __restrict__ in_dcq, const int* __restrict__ in_db,
    const float* __restrict__ emb, float* __restrict__ x_all, float* __restrict__ ytmp,
    float* __restrict__ inv_eq, float* __restrict__ inv_ed, float* __restrict__ inv_eb,
    float* __restrict__ zero_p, int nzero) {
    int blk = blockIdx.x;
    if (blk >= 2896) {                      // zero tail
        int i = (blk - 2896) * 256 + threadIdx.x;
        if (i < nzero) zero_p[i] = 0.f;
        return;
    }
    int t = blk * 256 + threadIdx.x;
    int r = t >> 5, c = t & 31;
    const int* idx; float* outp; float* invp; int lr;
    if (r < ROWS_DCQ)              { idx = in_dcq; outp = ytmp + (size_t)r * DD;  invp = nullptr; lr = r; }
    else if (r < ROWS_DCQ + ROWS_D){ idx = in_d;   outp = x_all + (size_t)r * DD; invp = inv_ed;  lr = r - ROWS_DCQ; }
    else if (r < R_ALL)            { idx = in_db;  outp = x_all + (size_t)r * DD; invp = inv_eb;  lr = r - (ROWS_DCQ + ROWS_D); }
    else                           { idx = in_q;   outp = x_all + (size_t)r * DD; invp = inv_eq;  lr = r - R_ALL; }
    float4 val = ((const float4*)(emb + (size_t)idx[lr] * DD))[c];
    ((float4*)outp)[c] = val;
    float ss = val.x * val.x + val.y * val.y + val.z * val.z + val.w * val.w;
    ss += __shfl_xor(ss, 1, 64);
    ss += __shfl_xor(ss, 2, 64);
    ss += __shfl_xor(ss, 4, 64);
    ss += __shfl_xor(ss, 8, 64);
    ss += __shfl_xor(ss, 16, 64);
    if (c == 0 && invp) invp[lr] = 1.0f / fmaxf(sqrtf(ss), 1e-12f);
}

// ---------------- linear 128->128 + relu, 8x8 register tile ----------------
__device__ __forceinline__ void linear_body(float* __restrict__ wT, float* __restrict__ bs,
                                            const float* __restrict__ in, const float* __restrict__ W,
                                            const float* __restrict__ bias, float* __restrict__ out,
                                            float* __restrict__ inv_out, int block) {
    int t = threadIdx.x;
    for (int i = t; i < DD * DD; i += 256) {
        int o = i >> 7, e = i & 127;
        wT[e * 132 + o] = W[i];
    }
    if (t < 128) bs[t] = bias[t];
    __syncthreads();
    int og = t & 15, rg = t >> 4;
    int rowbase = block * 128 + rg * 8;
    f2 acc[8][4];
#pragma unroll
    for (int r = 0; r < 8; r++)
#pragma unroll
        for (int p = 0; p < 4; p++) acc[r][p] = f2{0.f, 0.f};
    for (int e4 = 0; e4 < 32; e4++) {
        float4 xv[8];
#pragma unroll
        for (int r = 0; r < 8; r++)
            xv[r] = *(const float4*)&in[(size_t)(rowbase + r) * DD + 4 * e4];
#pragma unroll
        for (int ee = 0; ee < 4; ee++) {
            int e = 4 * e4 + ee;
            float4 wa = *(const float4*)&wT[e * 132 + 8 * og];
            float4 wb = *(const float4*)&wT[e * 132 + 8 * og + 4];
            f2 w0 = {wa.x, wa.y}, w1 = {wa.z, wa.w}, w2 = {wb.x, wb.y}, w3 = {wb.z, wb.w};
#pragma unroll
            for (int r = 0; r < 8; r++) {
                float x = ((const float*)&xv[r])[ee];
                f2 x2 = {x, x};
                acc[r][0] = __builtin_elementwise_fma(x2, w0, acc[r][0]);
                acc[r][1] = __builtin_elementwise_fma(x2, w1, acc[r][1]);
                acc[r][2] = __builtin_elementwise_fma(x2, w2, acc[r][2]);
                acc[r][3] = __builtin_elementwise_fma(x2, w3, acc[r][3]);
            }
        }
    }
    float4 ba = *(const float4*)&bs[8 * og];
    float4 bbv = *(const float4*)&bs[8 * og + 4];
    float ss[8];
#pragma unroll
    for (int r = 0; r < 8; r++) {
        float o0 = fmaxf(acc[r][0].x + ba.x, 0.f);
        float o1 = fmaxf(acc[r][0].y + ba.y, 0.f);
        float o2 = fmaxf(acc[r][1].x + ba.z, 0.f);
        float o3 = fmaxf(acc[r][1].y + ba.w, 0.f);
        float o4 = fmaxf(acc[r][2].x + bbv.x, 0.f);
        float o5 = fmaxf(acc[r][2].y + bbv.y, 0.f);
        float o6 = fmaxf(acc[r][3].x + bbv.z, 0.f);
        float o7 = fmaxf(acc[r][3].y + bbv.w, 0.f);
        float4 s1 = {o0, o1, o2, o3}, s2 = {o4, o5, o6, o7};
        float* op = out + (size_t)(rowbase + r) * DD + 8 * og;
        *(float4*)op = s1;
        *(float4*)(op + 4) = s2;
        ss[r] = o0 * o0 + o1 * o1 + o2 * o2 + o3 * o3 + o4 * o4 + o5 * o5 + o6 * o6 + o7 * o7;
    }
    if (inv_out) {
#pragma unroll
        for (int r = 0; r < 8; r++) {
            ss[r] += __shfl_xor(ss[r], 1, 64);
            ss[r] += __shfl_xor(ss[r], 2, 64);
            ss[r] += __shfl_xor(ss[r], 4, 64);
            ss[r] += __shfl_xor(ss[r], 8, 64);
        }
#pragma unroll
        for (int r = 0; r < 8; r++)
            if (og == r) inv_out[rowbase + r] = 1.0f / fmaxf(sqrtf(ss[r]), 1e-12f);
    }
}

__global__ __launch_bounds__(256) void lin_kernel(const float* __restrict__ in, const float* __restrict__ W,
                                                  const float* __restrict__ bias, float* __restrict__ out,
                                                  float* __restrict__ inv_out) {
    __shared__ float wT[DD * 132];
    __shared__ float bs[DD];
    linear_body(wT, bs, in, W, bias, out, inv_out, blockIdx.x);
}

__global__ __launch_bounds__(256) void qkv_all(const float* __restrict__ x,
                                               const float* __restrict__ Wq, const float* __restrict__ bq,
                                               const float* __restrict__ Wk, const float* __restrict__ bk,
                                               const float* __restrict__ Wv, const float* __restrict__ bv,
                                               float* __restrict__ q, float* __restrict__ k, float* __restrict__ v) {
    __shared__ float wT[DD * 132];
    __shared__ float bs[DD];
    int sel = blockIdx.x / 176, blk = blockIdx.x % 176;
    const float* W = (sel == 0) ? Wq : (sel == 1) ? Wk : Wv;
    const float* B = (sel == 0) ? bq : (sel == 1) ? bk : bv;
    float* O = (sel == 0) ? q : (sel == 1) ? k : v;
    linear_body(wT, bs, x, W, B, O, nullptr, blk);
}

// ---------------- L=512 attention v6 (measured 82 µs): NR=4 rows/lane, K+V in LDS ----
// 512 threads = 8 waves = 2 qw x 4 kg. Lane owns rows r0,r0+64 (pair0), r0+128,r0+192
// (pair1), r0 = qw*256+lane. Softmax without max-shift: algebraically identical.
__device__ __forceinline__ void attn512_v6(float* __restrict__ sm,
                                           const float* __restrict__ q, const float* __restrict__ k,
                                           const float* __restrict__ v, float* __restrict__ y,
                                           int b, int h) {
    float* ks = sm;
    float* vs = sm + 512 * 16;
    int t = threadIdx.x;
    const size_t base = (size_t)b * 512 * DD + h * 16;
    for (int i = t; i < 512 * 4; i += 512) {
        int j = i >> 2, c = i & 3;
        *(float4*)&ks[j * 16 + 4 * c] = *(const float4*)&k[base + (size_t)j * DD + 4 * c];
        *(float4*)&vs[j * 16 + 4 * c] = *(const float4*)&v[base + (size_t)j * DD + 4 * c];
    }
    int w = t >> 6, lane = t & 63;
    int kg = w & 3, qw = w >> 2;
    int r0 = qw * 256 + lane;
    f2 qv[2][16];
#pragma unroll
    for (int p = 0; p < 2; p++) {
        const float* qa = q + base + (size_t)(r0 + p * 128) * DD;
        const float* qb2 = qa + 64 * DD;
#pragma unroll
        for (int c = 0; c < 4; c++) {
            float4 va = *(const float4*)(qa + 4 * c);
            float4 vb = *(const float4*)(qb2 + 4 * c);
            qv[p][4 * c + 0] = f2{va.x * 0.25f, vb.x * 0.25f};
            qv[p][4 * c + 1] = f2{va.y * 0.25f, vb.y * 0.25f};
            qv[p][4 * c + 2] = f2{va.z * 0.25f, vb.z * 0.25f};
            qv[p][4 * c + 3] = f2{va.w * 0.25f, vb.w * 0.25f};
        }
    }
    f2 acc[2][16];
    f2 l2[2] = {f2{0.f, 0.f}, f2{0.f, 0.f}};
#pragma unroll
    for (int p = 0; p < 2; p++)
#pragma unroll
        for (int e = 0; e < 16; e++) acc[p][e] = f2{0.f, 0.f};
    __syncthreads();
    int j0 = kg * 128;
    for (int j = j0; j < j0 + 128; j++) {
        float kk[16], vv[16];
#pragma unroll
        for (int c = 0; c < 4; c++) {
            *(float4*)&kk[4 * c] = *(const float4*)&ks[j * 16 + 4 * c];
            *(float4*)&vv[4 * c] = *(const float4*)&vs[j * 16 + 4 * c];
        }
        f2 d0a = qv[0][0] * f2{kk[0], kk[0]};
        f2 d1a = qv[0][1] * f2{kk[1], kk[1]};
        f2 d0b = qv[1][0] * f2{kk[0], kk[0]};
        f2 d1b = qv[1][1] * f2{kk[1], kk[1]};
#pragma unroll
        for (int e = 2; e < 16; e += 2) {
            d0a = __builtin_elementwise_fma(qv[0][e], f2{kk[e], kk[e]}, d0a);
            d1a = __builtin_elementwise_fma(qv[0][e + 1], f2{kk[e + 1], kk[e + 1]}, d1a);
            d0b = __builtin_elementwise_fma(qv[1][e], f2{kk[e], kk[e]}, d0b);
            d1b = __builtin_elementwise_fma(qv[1][e + 1], f2{kk[e + 1], kk[e + 1]}, d1b);
        }
        f2 da = d0a + d1a, db = d0b + d1b;
        f2 pa = {__expf(da.x), __expf(da.y)};
        f2 pb = {__expf(db.x), __expf(db.y)};
        l2[0] += pa;
        l2[1] += pb;
#pragma unroll
        for (int e = 0; e < 16; e++) {
            f2 ve = {vv[e], vv[e]};
            acc[0][e] = __builtin_elementwise_fma(pa, ve, acc[0][e]);
            acc[1][e] = __builtin_elementwise_fma(pb, ve, acc[1][e]);
        }
    }
    __syncthreads();   // staging dead; reuse sm for partials: 512 rows x 20 floats
#pragma unroll
    for (int g = 1; g < 4; g++) {
        if (kg == g) {
#pragma unroll
            for (int p = 0; p < 2; p++) {
                int ra = r0 + p * 128;
                float* pa = &sm[ra * 20];
                float* pb = &sm[(ra + 64) * 20];
#pragma unroll
                for (int e = 0; e < 16; e++) { pa[e] = acc[p][e].x; pb[e] = acc[p][e].y; }
                pa[16] = l2[p].x;
                pb[16] = l2[p].y;
            }
        }
        __syncthreads();
        if (kg == 0) {
#pragma unroll
            for (int p = 0; p < 2; p++) {
                int ra = r0 + p * 128;
                const float* pa = &sm[ra * 20];
                const float* pb = &sm[(ra + 64) * 20];
#pragma unroll
                for (int e = 0; e < 16; e++) { acc[p][e].x += pa[e]; acc[p][e].y += pb[e]; }
                l2[p].x += pa[16];
                l2[p].y += pb[16];
            }
        }
        __syncthreads();
    }
    if (kg == 0) {
#pragma unroll
        for (int p = 0; p < 2; p++) {
            float ix = 1.0f / l2[p].x, iy = 1.0f / l2[p].y;
            float o0[16], o1[16];
#pragma unroll
            for (int e = 0; e < 16; e++) { o0[e] = acc[p][e].x * ix; o1[e] = acc[p][e].y * iy; }
            float* yp0 = y + base + (size_t)(r0 + p * 128) * DD;
            float* yp1 = yp0 + 64 * DD;
#pragma unroll
            for (int c = 0; c < 4; c++) {
                *(float4*)(yp0 + 4 * c) = *(const float4*)&o0[4 * c];
                *(float4*)(yp1 + 4 * c) = *(const float4*)&o1[4 * c];
            }
        }
    }
}

// ---------------- small-L attention (e-split, 8 waves, K+V in LDS) ----------------
template <int L, int NQ>
__device__ __forceinline__ void attn_body(float* __restrict__ sm, const float* __restrict__ q,
                                          const float* __restrict__ k, const float* __restrict__ v,
                                          float* __restrict__ y, int b, int h) {
    constexpr int WAVES = 8;
    constexpr int WQ = L / (32 * NQ);
    constexpr int KG = WAVES / WQ;
    constexpr int KPG = L / KG;
    float* ks = sm;
    float* vs = sm + L * 16;
    int t = threadIdx.x;
    const size_t base = (size_t)b * L * DD + h * 16;
    for (int i = t; i < L * 4; i += 512) {
        int j = i >> 2, c = i & 3;
        *(float4*)&ks[j * 16 + 4 * c] = *(const float4*)&k[base + (size_t)j * DD + 4 * c];
        *(float4*)&vs[j * 16 + 4 * c] = *(const float4*)&v[base + (size_t)j * DD + 4 * c];
    }
    int w = t >> 6, lane = t & 63;
    int ls = lane & 31, eh = lane >> 5;
    int kg = w % KG, qw = w / KG;
    int qb2 = qw * 32 * NQ;
    f2 qv[NQ][4];
#pragma unroll
    for (int n = 0; n < NQ; n++) {
        int qr = qb2 + ls + 32 * n;
        const float* qp = q + base + (size_t)qr * DD + eh * 8;
        float4 a = *(const float4*)qp;
        float4 b4 = *(const float4*)(qp + 4);
        qv[n][0] = f2{a.x, a.y};   qv[n][1] = f2{a.z, a.w};
        qv[n][2] = f2{b4.x, b4.y}; qv[n][3] = f2{b4.z, b4.w};
    }
    f2 acc[NQ][4];
    float l[NQ];
#pragma unroll
    for (int n = 0; n < NQ; n++) {
#pragma unroll
        for (int m = 0; m < 4; m++) acc[n][m] = f2{0.f, 0.f};
        l[n] = 0.f;
    }
    __syncthreads();
    for (int j = kg * KPG; j < (kg + 1) * KPG; j++) {
        float4 ka = *(const float4*)&ks[j * 16 + eh * 8];
        float4 kb2 = *(const float4*)&ks[j * 16 + eh * 8 + 4];
        float4 va = *(const float4*)&vs[j * 16 + eh * 8];
        float4 vb2 = *(const float4*)&vs[j * 16 + eh * 8 + 4];
        f2 kk0 = {ka.x, ka.y}, kk1 = {ka.z, ka.w}, kk2 = {kb2.x, kb2.y}, kk3 = {kb2.z, kb2.w};
        f2 vv0 = {va.x, va.y}, vv1 = {va.z, va.w}, vv2 = {vb2.x, vb2.y}, vv3 = {vb2.z, vb2.w};
#pragma unroll
        for (int n = 0; n < NQ; n++) {
            f2 d2 = qv[n][0] * kk0;
            d2 = __builtin_elementwise_fma(qv[n][1], kk1, d2);
            d2 = __builtin_elementwise_fma(qv[n][2], kk2, d2);
            d2 = __builtin_elementwise_fma(qv[n][3], kk3, d2);
            float sh = d2.x + d2.y;
            float s = sh + __shfl_xor(sh, 32, 64);
            float p = __expf(s * 0.25f);
            l[n] += p;
            f2 p2 = {p, p};
            acc[n][0] = __builtin_elementwise_fma(p2, vv0, acc[n][0]);
            acc[n][1] = __builtin_elementwise_fma(p2, vv1, acc[n][1]);
            acc[n][2] = __builtin_elementwise_fma(p2, vv2, acc[n][2]);
            acc[n][3] = __builtin_elementwise_fma(p2, vv3, acc[n][3]);
        }
    }
    __syncthreads();
    if (kg > 0) {
#pragma unroll
        for (int n = 0; n < NQ; n++) {
            int qr = qb2 + ls + 32 * n;
            float* pp = &sm[((kg - 1) * L + qr) * 20 + eh * 10];
            *(f2*)&pp[0] = acc[n][0];
            *(f2*)&pp[2] = acc[n][1];
            *(f2*)&pp[4] = acc[n][2];
            *(f2*)&pp[6] = acc[n][3];
            pp[8] = l[n];
        }
    }
    __syncthreads();
    if (kg == 0) {
#pragma unroll
        for (int n = 0; n < NQ; n++) {
            int qr = qb2 + ls + 32 * n;
            f2 a0 = acc[n][0], a1 = acc[n][1], a2 = acc[n][2], a3 = acc[n][3];
            float lt = l[n];
#pragma unroll
            for (int g = 1; g < KG; g++) {
                const float* pp = &sm[((g - 1) * L + qr) * 20 + eh * 10];
                a0 += *(const f2*)&pp[0];
                a1 += *(const f2*)&pp[2];
                a2 += *(const f2*)&pp[4];
                a3 += *(const f2*)&pp[6];
                lt += pp[8];
            }
            float inv = 1.0f / lt;
            float4 o1 = {a0.x * inv, a0.y * inv, a1.x * inv, a1.y * inv};
            float4 o2 = {a2.x * inv, a2.y * inv, a3.x * inv, a3.y * inv};
            float* yp = y + base + (size_t)qr * DD + eh * 8;
            *(float4*)yp = o1;
            *(float4*)(yp + 4) = o2;
        }
    }
}

// XCD swizzle: b = local&31 -> all 8 heads of a batch land on the same XCD.
__global__ __launch_bounds__(512, 2) void attn_all(const float* __restrict__ qb_, const float* __restrict__ kb_,
                                                   const float* __restrict__ vb_, float* __restrict__ yb_) {
    __shared__ float sm[16384];            // 64 KB
    int blk = blockIdx.x;
    if (blk < 256) {
        const size_t off = (size_t)(ROWS_DCQ + ROWS_D) * DD;
        attn512_v6(sm, qb_ + off, kb_ + off, vb_ + off, yb_ + off, blk & 31, blk >> 5);
    } else if (blk < 512) {
        int local = blk - 256;
        attn_body<128, 1>(sm, qb_, kb_, vb_, yb_, local & 31, local >> 5);
    } else {
        int local = blk - 512;
        const size_t off = (size_t)ROWS_DCQ * DD;
        attn_body<64, 1>(sm, qb_ + off, kb_ + off, vb_ + off, yb_ + off, local & 31, local >> 5);
    }
}

// ---------------- KNRM core: register-tiled sims + gaussian kernels ----------------
// RAW=true: atomically add raw ps sums (no log/mask) into out[qrow*11+kk] — used to
// split the d-range of one logical pass across blocks (log(Σ) done later in final).
template <int QPT, int DPT, bool RAW>
__device__ void knrm_core(float* __restrict__ sm,
                          const float* __restrict__ Q, const float* __restrict__ invQ,
                          const float* __restrict__ mq, int QL, int q0, int qbase,
                          const float* __restrict__ D, const float* __restrict__ invD,
                          const float* __restrict__ md, int DL, int dbase, int mdbase,
                          float* __restrict__ out) {
    constexpr int QT = QPT * 16, DT = DPT * 16;
    float* qtile = sm;
    float* dtile = qtile + QT * 132;
    float* mdv = dtile + DT * 132;
    float* red = mdv + DT;
    float* outred = red + 4 * 16 * QPT * 11;
    const float MUc[11] = {1.0f, 0.9f, 0.7f, 0.5f, 0.3f, 0.1f, -0.1f, -0.3f, -0.5f, -0.7f, -0.9f};
    const float NC[11]  = {-500000.0f, -50.f, -50.f, -50.f, -50.f, -50.f, -50.f, -50.f, -50.f, -50.f, -50.f};
    int t = threadIdx.x;
    int tq = t & 15, td = t >> 4;
    if (!RAW && t < 11) outred[t] = 0.f;
    for (int i = t; i < QT * 32; i += 256) {
        int r = i >> 5, c = i & 31;
        int qrow = q0 + r;
        float4 val = make_float4(0.f, 0.f, 0.f, 0.f);
        if (qrow < QL) {
            float s = invQ[qbase + qrow];
            float4 g = *(const float4*)(Q + (size_t)(qbase + qrow) * DD + 4 * c);
            val = make_float4(g.x * s, g.y * s, g.z * s, g.w * s);
        }
        *(float4*)&qtile[r * 132 + 4 * c] = val;
    }
    float ps[QPT][11];
#pragma unroll
    for (int i = 0; i < QPT; i++)
#pragma unroll
        for (int kk = 0; kk < 11; kk++) ps[i][kk] = 0.f;

    for (int d0 = 0; d0 < DL; d0 += DT) {
        for (int i = t; i < DT * 32; i += 256) {
            int r = i >> 5, c = i & 31;
            int drow = d0 + r;
            float4 val = make_float4(0.f, 0.f, 0.f, 0.f);
            if (drow < DL) {
                float s = invD[dbase + drow];
                float4 g = *(const float4*)(D + (size_t)(dbase + drow) * DD + 4 * c);
                val = make_float4(g.x * s, g.y * s, g.z * s, g.w * s);
            }
            *(float4*)&dtile[r * 132 + 4 * c] = val;
        }
        if (t < DT) mdv[t] = (d0 + t < DL) ? md[mdbase + d0 + t] : 0.f;
        __syncthreads();
        float dot[QPT][DPT];
#pragma unroll
        for (int i = 0; i < QPT; i++)
#pragma unroll
            for (int j = 0; j < DPT; j++) dot[i][j] = 0.f;
#pragma unroll 2
        for (int e4 = 0; e4 < 32; e4++) {
            float4 qv[QPT], dv[DPT];
#pragma unroll
            for (int i = 0; i < QPT; i++) qv[i] = *(const float4*)&qtile[(tq + 16 * i) * 132 + 4 * e4];
#pragma unroll
            for (int j = 0; j < DPT; j++) dv[j] = *(const float4*)&dtile[(td + 16 * j) * 132 + 4 * e4];
#pragma unroll
            for (int i = 0; i < QPT; i++)
#pragma unroll
                for (int j = 0; j < DPT; j++)
                    dot[i][j] += qv[i].x * dv[j].x + qv[i].y * dv[j].y + qv[i].z * dv[j].z + qv[i].w * dv[j].w;
        }
#pragma unroll
        for (int j = 0; j < DPT; j++) {
            float m = mdv[td + 16 * j];
#pragma unroll
            for (int i = 0; i < QPT; i++) {
                float sim = dot[i][j];
#pragma unroll
                for (int kk = 0; kk < 11; kk++) {
                    float df = sim - MUc[kk];
                    ps[i][kk] = fmaf(__expf(df * df * NC[kk]), m, ps[i][kk]);
                }
            }
        }
        __syncthreads();
    }
#pragma unroll
    for (int i = 0; i < QPT; i++)
#pragma unroll
        for (int kk = 0; kk < 11; kk++) {
            ps[i][kk] += __shfl_xor(ps[i][kk], 16, 64);
            ps[i][kk] += __shfl_xor(ps[i][kk], 32, 64);
        }
    int w = t >> 6;
    if ((t & 63) < 16) {
#pragma unroll
        for (int i = 0; i < QPT; i++)
#pragma unroll
            for (int kk = 0; kk < 11; kk++) red[(w * 16 + tq) * (QPT * 11) + i * 11 + kk] = ps[i][kk];
    }
    __syncthreads();
    for (int i = t; i < 16 * QPT * 11; i += 256) {
        int tq2 = i / (QPT * 11);
        int rem = i - tq2 * (QPT * 11);
        int qi = rem / 11, kk = rem - qi * 11;
        float s = red[(0 * 16 + tq2) * (QPT * 11) + qi * 11 + kk] + red[(1 * 16 + tq2) * (QPT * 11) + qi * 11 + kk]
                + red[(2 * 16 + tq2) * (QPT * 11) + qi * 11 + kk] + red[(3 * 16 + tq2) * (QPT * 11) + qi * 11 + kk];
        int qrow = q0 + tq2 + 16 * qi;
        if (qrow < QL) {
            if (RAW) {
                atomicAdd(&out[qrow * 11 + kk], s);
            } else {
                float lps = logf(fmaxf(s, 1e-10f)) * mq[qbase + qrow] * 0.01f;
                atomicAdd(&outred[kk], lps);
            }
        }
    }
    if (!RAW) {
        __syncthreads();
        if (t < 11) atomicAdd(&out[t], outred[t]);
    }
}

// grid: [0,32) qd | [32,544) qb raw-chunks (16 per b) | [544,5408) kq/kd/kb (19 per (b,inst))
__global__ __launch_bounds__(256) void knrm_all(
    const float* __restrict__ eq, const float* __restrict__ inv_eq, const float* __restrict__ mask_q,
    const float* __restrict__ ed, const float* __restrict__ inv_ed, const float* __restrict__ mask_d,
    const float* __restrict__ eb, const float* __restrict__ inv_eb, const float* __restrict__ mask_db,
    const float* __restrict__ enc_d, const float* __restrict__ inv_encd,
    const float* __restrict__ enc_b, const float* __restrict__ inv_encb,
    const float* __restrict__ enc_dcq, const float* __restrict__ inv_encdcq, const float* __restrict__ mask_dcq,
    float* __restrict__ qdk, float* __restrict__ ps_qb,
    float* __restrict__ kq, float* __restrict__ kd, float* __restrict__ kb) {
    __shared__ float sm[9920];
    int blk = blockIdx.x;
    if (blk < 32) {
        int b = blk;
        knrm_core<2, 2, false>(sm, eq, inv_eq, mask_q, QL_, 0, b * QL_,
                               ed, inv_ed, mask_d, DL_, b * DL_, b * DL_, qdk + b * 11);
    } else if (blk < 544) {
        int u = blk - 32;
        int b = u & 31, ch = u >> 5;      // 16 chunks of 32 keys over BL=512
        knrm_core<2, 2, true>(sm, eq, inv_eq, mask_q, QL_, 0, b * QL_,
                              eb, inv_eb, mask_db, 32, b * BL_ + ch * 32, b * BL_ + ch * 32,
                              ps_qb + b * (QL_ * 11));
    } else {
        int u = blk - 544;
        int g = u / 19, sub = u % 19;
        int b = g & 31, inst = g >> 5;
        int dbase = b * (MN_ * ML_) + inst * ML_;
        if (sub == 0)
            knrm_core<2, 1, false>(sm, eq, inv_eq, mask_q, QL_, 0, b * QL_,
                                   enc_dcq, inv_encdcq, mask_dcq, ML_, dbase, dbase,
                                   kq + (size_t)(inst * BB + b) * 11);
        else if (sub < 3)
            knrm_core<2, 1, false>(sm, enc_d, inv_encd, mask_d, DL_, (sub - 1) * 32, b * DL_,
                                   enc_dcq, inv_encdcq, mask_dcq, ML_, dbase, dbase,
                                   kd + (size_t)(inst * BB + b) * 11);
        else
            knrm_core<2, 1, false>(sm, enc_b, inv_encb, mask_db, BL_, (sub - 3) * 32, b * BL_,
                                   enc_dcq, inv_encdcq, mask_dcq, ML_, dbase, dbase,
                                   kb + (size_t)(inst * BB + b) * 11);
    }
}

// ---------------- final combine (also finishes qb: log of summed ps partials) --------
__device__ inline float dot11(const float* w, const float* x) {
    float s = 0.f;
#pragma unroll
    for (int k = 0; k < 11; k++) s += w[k] * x[k];
    return s;
}

__global__ __launch_bounds__(384) void final_kernel(
    const float* __restrict__ qdk, const float* __restrict__ ps_qb, const float* __restrict__ mask_q,
    const float* __restrict__ kq, const float* __restrict__ kd, const float* __restrict__ kb,
    const float* qdW, const float* qdb, const float* qbW, const float* qbb,
    const float* qcqW, const float* qcqb, const float* dcqW, const float* dcqb,
    const float* bcqW, const float* bcqb, const float* expW, const float* expb,
    const float* combW, const float* combb, float* __restrict__ out) {
    __shared__ float qbk_s[BB * 11];
    int t = threadIdx.x;
    if (t < BB * 11) {
        int b = t / 11, kk = t % 11;
        float s = 0.f;
        for (int qq = 0; qq < QL_; qq++)
            s += logf(fmaxf(ps_qb[b * (QL_ * 11) + qq * 11 + kk], 1e-10f)) * mask_q[b * QL_ + qq];
        qbk_s[t] = s * 0.01f;
    }
    __syncthreads();
    int b = t;
    if (b >= BB) return;
    float qd = tanhf(dot11(qdW, qdk + b * 11) + qdb[0]);
    float qb = tanhf(dot11(qbW, qbk_s + b * 11) + qbb[0]);
    float qcqd = 0.f, qcqb2 = 0.f;
    for (int i = 0; i < MN_; i++) {
        int base = (i * BB + b) * 11;
        float r  = tanhf(dot11(qcqW, kq + base) + qcqb[0]);
        float da = tanhf(dot11(dcqW, kd + base) + dcqb[0]);
        float ba = tanhf(dot11(bcqW, kb + base) + bcqb[0]);
        qcqd += r * da;
        qcqb2 += r * ba;
    }
    float qcq = expW[0] * qcqd + expW[1] * qcqb2 + expb[0];
    out[b] = tanhf(combW[0] * qd + combW[1] * qb + combW[2] * qcq + combb[0]);
}

extern "C" void kernel_launch(void* const* d_in, const int* in_sizes, int n_in,
                              void* d_out, int out_size, void* d_ws, size_t ws_size,
                              hipStream_t stream) {
    const int*   in_q    = (const int*)d_in[0];
    const int*   in_d    = (const int*)d_in[1];
    const int*   in_dcq  = (const int*)d_in[2];
    const int*   in_db   = (const int*)d_in[3];
    const float* mask_q  = (const float*)d_in[4];
    const float* mask_d  = (const float*)d_in[5];
    const float* mask_dcq= (const float*)d_in[6];
    const float* mask_db = (const float*)d_in[7];
    const float* emb     = (const float*)d_in[8];
    const float* Wq = (const float*)d_in[9];   const float* bq = (const float*)d_in[10];
    const float* Wk = (const float*)d_in[11];  const float* bk = (const float*)d_in[12];
    const float* Wv = (const float*)d_in[13];  const float* bv = (const float*)d_in[14];
    const float* Wo = (const float*)d_in[15];  const float* bo = (const float*)d_in[16];
    const float* tW = (const float*)d_in[17];  const float* tb = (const float*)d_in[18];
    const float* qdW = (const float*)d_in[19]; const float* qdb = (const float*)d_in[20];
    const float* qbW = (const float*)d_in[21]; const float* qbb = (const float*)d_in[22];
    const float* qcqW = (const float*)d_in[23];const float* qcqb = (const float*)d_in[24];
    const float* dcqW = (const float*)d_in[25];const float* dcqb = (const float*)d_in[26];
    const float* bcqW = (const float*)d_in[27];const float* bcqb = (const float*)d_in[28];
    const float* expW = (const float*)d_in[29];const float* expb = (const float*)d_in[30];
    const float* combW = (const float*)d_in[31];const float* combb = (const float*)d_in[32];
    float* out = (float*)d_out;

    float* ws = (float*)d_ws;
    size_t off = 0;
    auto alloc = [&](size_t n) { float* p = ws + off; off += n; return p; };
    float* x_all = alloc((size_t)R_GATHER * DD);   // [dcq|d|b|eq] embeddings / projected dcq
    float* qbuf  = alloc((size_t)R_ALL * DD);      // q proj; attn writes y in-place here
    float* kbuf  = alloc((size_t)R_ALL * DD);      // gather tmp -> k proj -> enc_all
    float* vbuf  = alloc((size_t)R_ALL * DD);
    float* inv_eq  = alloc(ROWS_EQ);
    float* inv_ed  = alloc(ROWS_D);
    float* inv_eb  = alloc(ROWS_B);
    float* inv_enc = alloc(R_ALL);
    float* qdk   = alloc(BB * 11);                 // [qdk|kq|kd|kb|ps_qb] contiguous, zeroed in gather
    float* kq    = alloc(MN_ * BB * 11);
    float* kd    = alloc(MN_ * BB * 11);
    float* kb    = alloc(MN_ * BB * 11);
    float* ps_qb = alloc(BB * QL_ * 11);
    (void)ws_size; (void)in_sizes; (void)n_in; (void)out_size;
    const int kZeroCount = BB * 11 + 3 * MN_ * BB * 11 + BB * QL_ * 11;   // 15840

    const float* eq      = x_all + (size_t)R_ALL * DD;
    const float* ed      = x_all + (size_t)ROWS_DCQ * DD;
    const float* eb      = x_all + (size_t)(ROWS_DCQ + ROWS_D) * DD;
    float* enc_all = kbuf;
    const float* enc_dcq = enc_all;
    const float* enc_d   = enc_all + (size_t)ROWS_DCQ * DD;
    const float* enc_b   = enc_all + (size_t)(ROWS_DCQ + ROWS_D) * DD;
    const float* inv_encdcq = inv_enc;
    const float* inv_encd   = inv_enc + ROWS_DCQ;
    const float* inv_encb   = inv_enc + ROWS_DCQ + ROWS_D;

    // 1. gathers + emb norms + zero knrm accumulators (dcq raw emb -> kbuf tmp)
    gather_all<<<2896 + (kZeroCount + 255) / 256, 256, 0, stream>>>(in_q, in_d, in_dcq, in_db, emb,
                                                                    x_all, kbuf, inv_eq, inv_ed, inv_eb,
                                                                    qdk, kZeroCount);
    // 2. t-projection: raw dcq emb (kbuf[0:4096]) -> x_all[0:4096]
    lin_kernel<<<ROWS_DCQ / 128, 256, 0, stream>>>(kbuf, tW, tb, x_all, nullptr);
    // 3. q/k/v projections over all 22528 rows in one launch
    qkv_all<<<3 * (R_ALL / 128), 256, 0, stream>>>(x_all, Wq, bq, Wk, bk, Wv, bv, qbuf, kbuf, vbuf);
    // 4. all three attentions in one launch; y written in-place into qbuf
    attn_all<<<768, 512, 0, stream>>>(qbuf, kbuf, vbuf, qbuf);
    // 5. out-projection over all rows + fused enc norms (kbuf becomes enc_all)
    lin_kernel<<<R_ALL / 128, 256, 0, stream>>>(qbuf, Wo, bo, enc_all, inv_enc);
    // 6. all 26 KNRM reductions (qb as raw-partial chunks)
    knrm_all<<<5408, 256, 0, stream>>>(eq, inv_eq, mask_q, ed, inv_ed, mask_d, eb, inv_eb, mask_db,
                                       enc_d, inv_encd, enc_b, inv_encb, enc_dcq, inv_encdcq, mask_dcq,
                                       qdk, ps_qb, kq, kd, kb);
    // 7. final combine (+ qb log-finish)
    final_kernel<<<1, 384, 0, stream>>>(qdk, ps_qb, mask_q, kq, kd, kb,
                                        qdW, qdb, qbW, qbb, qcqW, qcqb, dcqW, dcqb,
                                        bcqW, bcqb, expW, expb, combW, combb, out);
}